// Round 14
// baseline (450.362 us; speedup 1.0000x reference)
//
#include <hip/hip_runtime.h>

// ---------------------------------------------------------------------------
// CausalSelfAttention2: x@Wqkv -> rope -> 512x block-causal attn -> o@Wo ;
// plus learned time-pooled qb/kb/vb outputs.
// Sizes: B=4 T=4096 C=1024 H=16 G=8 HS=64 GT=512. d_out is FLOAT32.
// R20: launch fusion 8 -> 4 + within-XCD bn-major GEMM ordering.
//  (a) prep_kernel = cvt + Wqkv/Wo transpose + fc/fs transpose (block-range
//      dispatch; each range's code verbatim from the validated kernels).
//  (b) pools fused into attn launch as TAIL blocks (lin>=2048): backfills
//      attn's uneven 1-4-tile workload; pools math identical at 512 thr
//      (8x64 t-chunks; f32 partial-sum order change only).
//  (c) GEMM within-XCD order: hold one 256KB B-column-tile, sweep 16
//      A-panels (4MB ~ L2) -> A L2-resident across bn sweeps (was: hold A,
//      sweep 6.3MB B > L2 -> 228MB FETCH).
// R19 8-wave 32x64 core, R16 XCD split, R15 BK=64, R13/R14 attn unchanged.
// ---------------------------------------------------------------------------

typedef float  float4_t  __attribute__((ext_vector_type(4)));
typedef short  bfrag     __attribute__((ext_vector_type(8)));   // 8 bf16
typedef unsigned short ushort8 __attribute__((ext_vector_type(8)));

#define MFMA_BF16(A, B, C) __builtin_amdgcn_mfma_f32_16x16x32_bf16((A), (B), (C), 0, 0, 0)

__device__ __forceinline__ unsigned short f2bf(float f) {
  union { float f; unsigned u; } v; v.f = f;
  return (unsigned short)((v.u + 0x7FFFu + ((v.u >> 16) & 1u)) >> 16);   // RNE
}
__device__ __forceinline__ float bf2f(unsigned short h) {
  union { unsigned u; float f; } v; v.u = ((unsigned)h) << 16; return v.f;
}
// async global->LDS, 16B per lane; LDS dest = wave-uniform base + lane*16
__device__ __forceinline__ void async16(const void* g, void* l) {
  __builtin_amdgcn_global_load_lds(
      (const __attribute__((address_space(1))) unsigned int*)(unsigned long long)g,
      (__attribute__((address_space(3))) unsigned int*)(unsigned long long)l,
      16, 0, 0);
}

// ---------------------------------------------------------------------------
// prep: [0,8192) cvt x->xb ; [8192,11264) Wqkv^T ; [11264,12288) Wo^T ;
//       [12288,12544) fc/fs f32 transpose. 256 thr as (32,8).
__global__ __launch_bounds__(256) void prep_kernel(
    const float* __restrict__ x, unsigned short* __restrict__ xb,
    const float* __restrict__ Wqkv, unsigned short* __restrict__ wqkvT,
    const float* __restrict__ Wo, unsigned short* __restrict__ woT,
    const float* __restrict__ fc, const float* __restrict__ fs,
    float* __restrict__ fcT, float* __restrict__ fsT) {
  int idx = blockIdx.x;
  int tx = threadIdx.x, ty = threadIdx.y;
  int tid = ty * 32 + tx;
  if (idx < 8192) {                       // ---- cvt: 8 f32 -> 8 bf16 / thread
    int i = idx * 256 + tid;
    const float4_t* p = (const float4_t*)x + (size_t)i * 2;
    float4_t a = p[0], c = p[1];
    ushort8 r;
    r[0] = f2bf(a[0]); r[1] = f2bf(a[1]); r[2] = f2bf(a[2]); r[3] = f2bf(a[3]);
    r[4] = f2bf(c[0]); r[5] = f2bf(c[1]); r[6] = f2bf(c[2]); r[7] = f2bf(c[3]);
    *((ushort8*)xb + i) = r;
    return;
  }
  __shared__ float t[32][33];
  const float* in; float* outf = nullptr; unsigned short* outh = nullptr;
  int R, C, bx, by;
  if (idx < 11264)      { int k = idx - 8192;  in = Wqkv; outh = wqkvT; R = 1024; C = 3072; bx = k % 96; by = k / 96; }
  else if (idx < 12288) { int k = idx - 11264; in = Wo;   outh = woT;   R = 1024; C = 1024; bx = k % 32; by = k / 32; }
  else                  { int k = idx - 12288; in = (k >= 128) ? fs : fc; outf = (k >= 128) ? fsT : fcT;
                          R = 4096; C = 32; bx = 0; by = k & 127; }
  int bc = bx * 32, br = by * 32;
  for (int i = 0; i < 32; i += 8) t[ty + i][tx] = in[(size_t)(br + ty + i) * C + bc + tx];
  __syncthreads();
  if (outh) { for (int i = 0; i < 32; i += 8) outh[(size_t)(bc + ty + i) * R + br + tx] = f2bf(t[tx][ty + i]); }
  else      { for (int i = 0; i < 32; i += 8) outf[(size_t)(bc + ty + i) * R + br + tx] = t[tx][ty + i]; }
}

// ---------------------------------------------------------------------------
// Shared GEMM core: C128x128 tile, BK=64, 8 waves (each 32x64 = 2x4 frags).
// A [M,K] bf16 row-major, BT [N,K] bf16 row-major. 512 threads.
// LDS tile 128x64: slot s (16B) holds row s>>3, chunk (s&7)^((s>>3)&7).
__device__ __forceinline__ void gemm_core(const unsigned short* __restrict__ A,
                                          const unsigned short* __restrict__ BT,
                                          int bm0, int bn0, int K,
                                          unsigned short* As, unsigned short* Bs,
                                          float4_t acc[2][4]) {
  int tid = threadIdx.x, w = tid >> 6;
  int lane = tid & 63, quad = lane >> 4, l16 = lane & 15;
  int wm = w >> 1, wn = w & 1;                     // 4x2 wave grid, 32x64 each
  int r = tid >> 3, x = tid & 7;
  int sc = (x ^ (r & 7)) * 8;                      // swizzled source col
  for (int k0 = 0; k0 < K; k0 += 64) {
    __syncthreads();
#pragma unroll
    for (int c = 0; c < 2; ++c) {
      async16(&A [(size_t)(bm0 + c * 64 + r) * K + k0 + sc], &As[(size_t)(c * 512 + tid) * 8]);
      async16(&BT[(size_t)(bn0 + c * 64 + r) * K + k0 + sc], &Bs[(size_t)(c * 512 + tid) * 8]);
    }
    __syncthreads();
#pragma unroll
    for (int ks = 0; ks < 2; ++ks) {
      bfrag af[2], bf_[4];
#pragma unroll
      for (int i = 0; i < 2; ++i) {
        int rm = wm * 32 + i * 16 + l16;
        af[i]  = *(const bfrag*)&As[(size_t)(rm * 8 + ((ks * 4 + quad) ^ (rm & 7))) * 8];
      }
#pragma unroll
      for (int j = 0; j < 4; ++j) {
        int rn = wn * 64 + j * 16 + l16;
        bf_[j] = *(const bfrag*)&Bs[(size_t)(rn * 8 + ((ks * 4 + quad) ^ (rn & 7))) * 8];
      }
#pragma unroll
      for (int i = 0; i < 2; ++i)
#pragma unroll
        for (int j = 0; j < 4; ++j)
          acc[i][j] = MFMA_BF16(af[i], bf_[j], acc[i][j]);
    }
  }
}

// GEMM1: qkv = rope(x @ Wqkv) stored PLAIN row-major [16384][3072].
// R20: within-XCD bn-major order (hold B-column-tile, sweep A-panels).
__global__ __launch_bounds__(512, 4) void gemm1_kernel(const unsigned short* __restrict__ xb,
    const unsigned short* __restrict__ wqkvT,
    const float* __restrict__ fcT, const float* __restrict__ fsT,
    unsigned short* __restrict__ qkv) {
  __shared__ __align__(16) unsigned char smem[34816];        // max(As|Bs 32K, Es 34.8K)
  unsigned short* As = (unsigned short*)smem;
  unsigned short* Bs = (unsigned short*)(smem + 16384);
  float4_t acc[2][4];
  for (int i = 0; i < 2; ++i) for (int j = 0; j < 4; ++j)
    acc[i][j] = (float4_t){0.f, 0.f, 0.f, 0.f};
  int lin = blockIdx.y * 24 + blockIdx.x;          // 0..3071, x-fastest
  int q = lin & 7, rem = lin >> 3;                 // XCD q gets 384 blocks
  int bn0 = (rem / 16) * 128;                      // bn-major within XCD:
  int bm0 = (q * 16 + (rem & 15)) * 128;           // 16 A-panels per B-tile
  gemm_core(xb, wqkvT, bm0, bn0, 1024, As, Bs, acc);

  int tid = threadIdx.x, w = tid >> 6, lane = tid & 63, quad = lane >> 4, l16 = lane & 15;
  int wm = w >> 1, wn = w & 1;

  // ---- rope in registers (R3 numerics; fcT/fsT float4 loads over r) -------
  for (int i = 0; i < 2; ++i) {
    int t0 = (bm0 + wm * 32 + i * 16 + quad * 4) & 4095;   // r spans t0..t0+3
    for (int j = 0; j < 4; ++j) {
      int gcol = bn0 + wn * 64 + j * 16 + l16;    // wave-uniform branch (16-aligned)
      if (gcol < 2048) {
        int ci = (gcol & 63) >> 1;                // pair index 0..31 (per lane)
        const float4_t c4 = *(const float4_t*)&fcT[(size_t)ci * 4096 + t0];
        const float4_t s4 = *(const float4_t*)&fsT[(size_t)ci * 4096 + t0];
        for (int r = 0; r < 4; ++r) {
          float val = acc[i][j][r];
          float partner = __shfl_xor(val, 1);     // even<->odd channel pair
          float c = c4[r], s = s4[r];             // == fc[t*32+ci], fs[t*32+ci]
          acc[i][j][r] = (gcol & 1) ? fmaf(partner, s, val * c)
                                    : fmaf(-partner, s, val * c);
        }
      }
    }
  }

  // ---- LDS restage + coalesced plain stores -------------------------------
  // Es aliases As/Bs: barrier ensures all K-loop ds_reads done; after it each
  // wave's Es slice is private (R9-validated intra-wave LDS ordering).
  __syncthreads();
  float* Es = (float*)smem;
  float* slice = &Es[w * 1088];
  for (int i = 0; i < 2; ++i) {
    for (int j = 0; j < 4; ++j)
      for (int r = 0; r < 4; ++r)
        slice[(quad * 4 + r) * 68 + j * 16 + l16] = acc[i][j][r];
    for (int m = 0; m < 2; ++m) {
      int rl = m * 8 + (lane >> 3);               // 0..15 local row
      int cb = (lane & 7) * 8;                    // 8-aligned col base
      const float* rp = &slice[rl * 68 + cb];
      ushort8 outv;
      outv[0] = f2bf(rp[0]); outv[1] = f2bf(rp[1]);
      outv[2] = f2bf(rp[2]); outv[3] = f2bf(rp[3]);
      outv[4] = f2bf(rp[4]); outv[5] = f2bf(rp[5]);
      outv[6] = f2bf(rp[6]); outv[7] = f2bf(rp[7]);
      int grow = bm0 + wm * 32 + i * 16 + rl;     // = b*4096 + t
      int gcol = bn0 + wn * 64 + cb;              // 0..3071, 8-aligned
      *(ushort8*)&qkv[(size_t)grow * 3072 + gcol] = outv;
    }
  }
}

// GEMM2: out = o @ Wo, f32 store into d_out[0 .. 16777216). R20: bn-major.
__global__ __launch_bounds__(512, 4) void gemm2_kernel(const unsigned short* __restrict__ ob,
    const unsigned short* __restrict__ woT, float* __restrict__ outp) {
  __shared__ __align__(16) unsigned short As[128 * 64];
  __shared__ __align__(16) unsigned short Bs[128 * 64];
  float4_t acc[2][4];
  for (int i = 0; i < 2; ++i) for (int j = 0; j < 4; ++j)
    acc[i][j] = (float4_t){0.f, 0.f, 0.f, 0.f};
  int lin = blockIdx.y * 8 + blockIdx.x;           // 0..1023, x-fastest
  int q = lin & 7, rem = lin >> 3;                 // 128 blocks per XCD
  int bn0 = (rem / 16) * 128;                      // 0..7
  int bm0 = (q * 16 + (rem & 15)) * 128;
  gemm_core(ob, woT, bm0, bn0, 1024, As, Bs, acc);
  int tid = threadIdx.x, w = tid >> 6, lane = tid & 63, quad = lane >> 4, l16 = lane & 15;
  int wm = w >> 1, wn = w & 1;
  for (int i = 0; i < 2; ++i)
    for (int j = 0; j < 4; ++j)
      for (int r = 0; r < 4; ++r)
        outp[(size_t)(bm0 + wm * 32 + i * 16 + quad * 4 + r) * 1024 +
             bn0 + wn * 64 + j * 16 + l16] = acc[i][j][r];
}

// ---------------------------------------------------------------------------
// MFMA flash attention (lin<2048) + fused pools tail blocks (lin>=2048).
// attn: R13 structure (QBLK=128, 512 threads, 8 waves, 128-key tiles,
// ntiles = qt2+1) + R14 T14 async-STAGE split + R16 XCD swizzle.
// Inverse scramble map (R12-validated):
//   q/k row 'row': t = ((row&255)<<4)|h, col = (2g+(row>>8))*64 + hs (+1024 k)
//   v   row 'row': t = g*512+row,        col = 2048 + h*64 + hs
__global__ __launch_bounds__(512) void attn_kernel(const unsigned short* __restrict__ qkv,
    unsigned short* __restrict__ ob,
    const float* __restrict__ qp, const float* __restrict__ kp,
    const float* __restrict__ vp, float* __restrict__ outp) {
  __shared__ __align__(16) unsigned short Ks[128 * 64];      // 1024 swizzled 16B slots
  __shared__ __align__(16) unsigned short VTs[64 * 136];     // [hs][key 0..127], pad->136
  __shared__ __align__(16) unsigned short Ps[8 * 16 * 136];  // per-wave P[16 q][128 k]
  int lin = blockIdx.x;                            // 0..2495
  int tid = threadIdx.x;

  if (lin >= 2048) {               // ---- pooled qb/kb/vb (tail-fill blocks)
    float* red = (float*)Ks;       // 3*8*64 f32 = 6KB scratch in Ks
    int pid = lin - 2048;          // 0..447
    int g = pid % 7, h = (pid / 7) % 16, b = pid / 112;
    int hs = tid & 63, tc = tid >> 6;              // 8 chunks x 64 t
    const unsigned short* qb_ = qkv + ((size_t)b * 4096 + h) * 3072 + g * 128 + hs;
    const unsigned short* vb_ = qkv + ((size_t)(b * 4096 + g * 512)) * 3072 + 2048 + h * 64 + hs;
    float aq = 0.f, ak = 0.f, av = 0.f;
    for (int t = tc * 64; t < tc * 64 + 64; ++t) {
      size_t qoff = ((size_t)((t & 255) << 4)) * 3072 + (t >> 8) * 64;
      aq = fmaf(bf2f(qb_[qoff]), qp[t], aq);
      ak = fmaf(bf2f(qb_[qoff + 1024]), kp[t], ak);
      av = fmaf(bf2f(vb_[(size_t)t * 3072]), vp[t], av);
    }
    red[(0 * 8 + tc) * 64 + hs] = aq;
    red[(1 * 8 + tc) * 64 + hs] = ak;
    red[(2 * 8 + tc) * 64 + hs] = av;
    __syncthreads();
    if (tc < 3) {                                  // tc: 0=q 1=k 2=v
      float a = 0.f;
      for (int c = 0; c < 8; ++c) a += red[(tc * 8 + c) * 64 + hs];
      size_t oi = (((size_t)b * 16 + h) * 7 + g) * 64 + hs;
      size_t off = (tc == 0) ? 0 : (tc == 1) ? 28672 : 57344;
      outp[16777216 + off + oi] = a;
    }
    return;
  }

  int bx = (lin & 7) * 256 + (lin >> 3);           // XCD-contiguous bijection
  int qt2 = bx & 3, g = (bx >> 2) & 7, h = (bx >> 5) & 15, b = bx >> 9;
  int w = tid >> 6, lane = tid & 63, quad = lane >> 4, l16 = lane & 15;

  const unsigned short* QKb = qkv + ((size_t)b * 4096 + h) * 3072 + g * 128;
  const unsigned short* Vb  = qkv + ((size_t)(b * 4096 + g * 512)) * 3072 + 2048 + h * 64;

  int qrow = qt2 * 128 + w * 16 + l16;
  const unsigned short* Qr = QKb + ((size_t)((qrow & 255) << 4)) * 3072 + (qrow >> 8) * 64;
  bfrag qf0 = *(const bfrag*)&Qr[quad * 8];
  bfrag qf1 = *(const bfrag*)&Qr[32 + quad * 8];

  float4_t acc[4];
#pragma unroll
  for (int i = 0; i < 4; ++i) acc[i] = (float4_t){0.f, 0.f, 0.f, 0.f};
  float m_i[4] = {-1e30f, -1e30f, -1e30f, -1e30f};
  float l_i[4] = {0.f, 0.f, 0.f, 0.f};

  int skey = tid >> 3, sx = tid & 7, ss = sx ^ (skey & 7);   // K staging swizzle
  int kp2 = tid & 63, hsg = tid >> 6;                         // V staging split (8 hs each)
  unsigned short* Pw = &Ps[w * 2176];                         // 16*136
  int ntiles = qt2 + 1;

  ushort8 kreg0, kreg1, vreg0, vreg1;

  // prologue: load + write tile 0
  {
    int krow0 = skey, krow1 = 64 + skey;
    kreg0 = *(const ushort8*)&QKb[((size_t)((krow0 & 255) << 4)) * 3072 + (krow0 >> 8) * 64 + 1024 + ss * 8];
    kreg1 = *(const ushort8*)&QKb[((size_t)((krow1 & 255) << 4)) * 3072 + (krow1 >> 8) * 64 + 1024 + ss * 8];
    const unsigned short* vp0 = Vb + (size_t)(kp2 * 2) * 3072 + hsg * 8;
    vreg0 = *(const ushort8*)vp0;
    vreg1 = *(const ushort8*)(vp0 + 3072);
    *(ushort8*)&Ks[(size_t)(tid) * 8]       = kreg0;
    *(ushort8*)&Ks[(size_t)(512 + tid) * 8] = kreg1;
#pragma unroll
    for (int e = 0; e < 8; ++e)
      *(unsigned*)&VTs[(size_t)(hsg * 8 + e) * 136 + kp2 * 2] =
          (unsigned)vreg0[e] | ((unsigned)vreg1[e] << 16);
  }

  for (int kt = 0; kt < ntiles; ++kt) {
    __syncthreads();   // staged LDS writes for tile kt visible to all waves

    // ---- QK^T (reads Ks) ----
    float4_t s[8];
#pragma unroll
    for (int c = 0; c < 8; ++c) s[c] = (float4_t){0.f, 0.f, 0.f, 0.f};
    {
      int sl0 = l16 * 8 + (quad ^ (l16 & 7));          // hs 0..31, key l16+16c
      int sl1 = l16 * 8 + ((4 + quad) ^ (l16 & 7));    // hs 32..63
#pragma unroll
      for (int c = 0; c < 8; ++c) {
        s[c] = MFMA_BF16(qf0, *(const bfrag*)&Ks[(size_t)(sl0 + 128 * c) * 8], s[c]);
        s[c] = MFMA_BF16(qf1, *(const bfrag*)&Ks[(size_t)(sl1 + 128 * c) * 8], s[c]);
      }
    }

    // ---- issue next tile's global loads (latency hides under softmax+PV) --
    bool more = (kt + 1 < ntiles);
    if (more) {
      int kb = (kt + 1) * 128;
      int krow0 = kb + skey, krow1 = kb + 64 + skey;
      kreg0 = *(const ushort8*)&QKb[((size_t)((krow0 & 255) << 4)) * 3072 + (krow0 >> 8) * 64 + 1024 + ss * 8];
      kreg1 = *(const ushort8*)&QKb[((size_t)((krow1 & 255) << 4)) * 3072 + (krow1 >> 8) * 64 + 1024 + ss * 8];
      const unsigned short* vp0 = Vb + (size_t)(kb + kp2 * 2) * 3072 + hsg * 8;
      vreg0 = *(const ushort8*)vp0;
      vreg1 = *(const ushort8*)(vp0 + 3072);
    }

    // ---- online softmax ----
    int qa = qt2 * 128 + w * 16 + quad * 4;
    int kb0 = kt * 128 + l16;
#pragma unroll
    for (int r = 0; r < 4; ++r) {
      float vv[8];
#pragma unroll
      for (int c = 0; c < 8; ++c) {
        vv[c] = s[c][r] * 0.125f;
        if (kb0 + 16 * c > qa + r) vv[c] = -1e30f;
      }
      float tm = fmaxf(fmaxf(fmaxf(vv[0], vv[1]), fmaxf(vv[2], vv[3])),
                       fmaxf(fmaxf(vv[4], vv[5]), fmaxf(vv[6], vv[7])));
      tm = fmaxf(tm, __shfl_xor(tm, 1));
      tm = fmaxf(tm, __shfl_xor(tm, 2));
      tm = fmaxf(tm, __shfl_xor(tm, 4));
      tm = fmaxf(tm, __shfl_xor(tm, 8));
      float nm = fmaxf(m_i[r], tm);
      float alpha = __expf(m_i[r] - nm);
      m_i[r] = nm;
      float p[8], rs = 0.f;
#pragma unroll
      for (int c = 0; c < 8; ++c) { p[c] = __expf(vv[c] - nm); rs += p[c]; }
      rs += __shfl_xor(rs, 1);
      rs += __shfl_xor(rs, 2);
      rs += __shfl_xor(rs, 4);
      rs += __shfl_xor(rs, 8);
      l_i[r] = l_i[r] * alpha + rs;
      acc[0][r] *= alpha; acc[1][r] *= alpha; acc[2][r] *= alpha; acc[3][r] *= alpha;
      int pr = (quad * 4 + r) * 136 + l16;
#pragma unroll
      for (int c = 0; c < 8; ++c) Pw[pr + 16 * c] = f2bf(p[c]);
    }
    // No barrier: Pw is this wave's private slice; intra-wave LDS write->read
    // ordering is architectural (lgkmcnt).
    bfrag pf[4];
#pragma unroll
    for (int c = 0; c < 4; ++c)
      pf[c] = *(const bfrag*)&Pw[(size_t)l16 * 136 + 32 * c + quad * 8];
#pragma unroll
    for (int ht = 0; ht < 4; ++ht) {
#pragma unroll
      for (int c = 0; c < 4; ++c) {
        bfrag vf = *(const bfrag*)&VTs[(size_t)(ht * 16 + l16) * 136 + 32 * c + quad * 8];
        acc[ht] = MFMA_BF16(pf[c], vf, acc[ht]);
      }
    }

    __syncthreads();   // all LDS reads of tile kt complete
    if (more) {        // write tile kt+1 (visible after loop-top barrier)
      *(ushort8*)&Ks[(size_t)(tid) * 8]       = kreg0;
      *(ushort8*)&Ks[(size_t)(512 + tid) * 8] = kreg1;
#pragma unroll
      for (int e = 0; e < 8; ++e)
        *(unsigned*)&VTs[(size_t)(hsg * 8 + e) * 136 + kp2 * 2] =
            (unsigned)vreg0[e] | ((unsigned)vreg1[e] << 16);
    }
  }

  // o_final[b, g*512+gt, h*64+hs]
  int orow = b * 4096 + g * 512 + qt2 * 128 + w * 16 + quad * 4;
#pragma unroll
  for (int ht = 0; ht < 4; ++ht)
#pragma unroll
    for (int r = 0; r < 4; ++r)
      ob[(size_t)(orow + r) * 1024 + h * 64 + ht * 16 + l16] = f2bf(acc[ht][r] / l_i[r]);
}

// ---------------------------------------------------------------------------
extern "C" void kernel_launch(void* const* d_in, const int* in_sizes, int n_in,
                              void* d_out, int out_size, void* d_ws, size_t ws_size,
                              hipStream_t stream) {
  (void)in_sizes; (void)n_in; (void)out_size; (void)ws_size;
  const float* x    = (const float*)d_in[0];
  const float* Wqkv = (const float*)d_in[1];
  const float* Wo   = (const float*)d_in[2];
  const float* qp   = (const float*)d_in[3];
  const float* kp   = (const float*)d_in[4];
  const float* vp   = (const float*)d_in[5];
  const float* fc   = (const float*)d_in[6];
  const float* fs   = (const float*)d_in[7];
  float* outp = (float*)d_out;                     // f32 output (reference dtype)

  char* ws = (char*)d_ws;                          // 142.6 MiB used
  unsigned short* xb    = (unsigned short*)(ws);               // 33.5MB (o aliases it later)
  unsigned short* wqkvT = (unsigned short*)(ws + 33554432);    // 6.3MB
  unsigned short* woT   = (unsigned short*)(ws + 39845888);    // 2.1MB
  unsigned short* qkv   = (unsigned short*)(ws + 41943040);    // 100.7MB [16384][3072]
  unsigned short* ob    = xb;  // safe alias: xb fully consumed by gemm1 before attn writes

  // fcT/fsT scratch lives in d_out[0 .. 512K floats): dead until gemm2, which
  // runs LAST and overwrites it. 32x4096 f32 each.
  float* fcT = outp;
  float* fsT = outp + 131072;

  prep_kernel<<<12544, dim3(32, 8), 0, stream>>>(x, xb, Wqkv, wqkvT, Wo, woT,
                                                 fc, fs, fcT, fsT);
  gemm1_kernel<<<dim3(24, 128), 512, 0, stream>>>(xb, wqkvT, fcT, fsT, qkv);
  attn_kernel<<<2496, 512, 0, stream>>>(qkv, ob, qp, kp, vp, outp);
  gemm2_kernel<<<dim3(8, 128), 512, 0, stream>>>(ob, woT, outp);
}

// Round 15
// 449.683 us; speedup vs baseline: 1.0015x; 1.0015x over previous
//
#include <hip/hip_runtime.h>

// ---------------------------------------------------------------------------
// CausalSelfAttention2: x@Wqkv -> rope -> 512x block-causal attn -> o@Wo ;
// plus learned time-pooled qb/kb/vb outputs.
// Sizes: B=4 T=4096 C=1024 H=16 G=8 HS=64 GT=512. d_out is FLOAT32.
// R21: REVERT R20's bn-major GEMM ordering (regressed ~55-65us: concurrent
// working set 16 A-panels + 4 B-tiles = 5MB > 4MB L2 still thrashed, AND
// fast-varying bm scattered concurrent stores across 16 row-bands of qkv,
// wrecking DRAM write locality). GEMM decode back to R19-validated A-major
// swz. KEPT from R20 (evidence: attn+pools fused = 165.5us < separate):
//  (a) prep_kernel fusion (cvt + transposes, 1 launch),
//  (b) pools fused into attn launch as tail blocks.
// R19 8-wave 32x64 core, R16 XCD split, R15 BK=64, R13/R14 attn unchanged.
// ---------------------------------------------------------------------------

typedef float  float4_t  __attribute__((ext_vector_type(4)));
typedef short  bfrag     __attribute__((ext_vector_type(8)));   // 8 bf16
typedef unsigned short ushort8 __attribute__((ext_vector_type(8)));

#define MFMA_BF16(A, B, C) __builtin_amdgcn_mfma_f32_16x16x32_bf16((A), (B), (C), 0, 0, 0)

__device__ __forceinline__ unsigned short f2bf(float f) {
  union { float f; unsigned u; } v; v.f = f;
  return (unsigned short)((v.u + 0x7FFFu + ((v.u >> 16) & 1u)) >> 16);   // RNE
}
__device__ __forceinline__ float bf2f(unsigned short h) {
  union { unsigned u; float f; } v; v.u = ((unsigned)h) << 16; return v.f;
}
// async global->LDS, 16B per lane; LDS dest = wave-uniform base + lane*16
__device__ __forceinline__ void async16(const void* g, void* l) {
  __builtin_amdgcn_global_load_lds(
      (const __attribute__((address_space(1))) unsigned int*)(unsigned long long)g,
      (__attribute__((address_space(3))) unsigned int*)(unsigned long long)l,
      16, 0, 0);
}

// ---------------------------------------------------------------------------
// prep: [0,8192) cvt x->xb ; [8192,11264) Wqkv^T ; [11264,12288) Wo^T ;
//       [12288,12544) fc/fs f32 transpose. 256 thr as (32,8).
__global__ __launch_bounds__(256) void prep_kernel(
    const float* __restrict__ x, unsigned short* __restrict__ xb,
    const float* __restrict__ Wqkv, unsigned short* __restrict__ wqkvT,
    const float* __restrict__ Wo, unsigned short* __restrict__ woT,
    const float* __restrict__ fc, const float* __restrict__ fs,
    float* __restrict__ fcT, float* __restrict__ fsT) {
  int idx = blockIdx.x;
  int tx = threadIdx.x, ty = threadIdx.y;
  int tid = ty * 32 + tx;
  if (idx < 8192) {                       // ---- cvt: 8 f32 -> 8 bf16 / thread
    int i = idx * 256 + tid;
    const float4_t* p = (const float4_t*)x + (size_t)i * 2;
    float4_t a = p[0], c = p[1];
    ushort8 r;
    r[0] = f2bf(a[0]); r[1] = f2bf(a[1]); r[2] = f2bf(a[2]); r[3] = f2bf(a[3]);
    r[4] = f2bf(c[0]); r[5] = f2bf(c[1]); r[6] = f2bf(c[2]); r[7] = f2bf(c[3]);
    *((ushort8*)xb + i) = r;
    return;
  }
  __shared__ float t[32][33];
  const float* in; float* outf = nullptr; unsigned short* outh = nullptr;
  int R, C, bx, by;
  if (idx < 11264)      { int k = idx - 8192;  in = Wqkv; outh = wqkvT; R = 1024; C = 3072; bx = k % 96; by = k / 96; }
  else if (idx < 12288) { int k = idx - 11264; in = Wo;   outh = woT;   R = 1024; C = 1024; bx = k % 32; by = k / 32; }
  else                  { int k = idx - 12288; in = (k >= 128) ? fs : fc; outf = (k >= 128) ? fsT : fcT;
                          R = 4096; C = 32; bx = 0; by = k & 127; }
  int bc = bx * 32, br = by * 32;
  for (int i = 0; i < 32; i += 8) t[ty + i][tx] = in[(size_t)(br + ty + i) * C + bc + tx];
  __syncthreads();
  if (outh) { for (int i = 0; i < 32; i += 8) outh[(size_t)(bc + ty + i) * R + br + tx] = f2bf(t[tx][ty + i]); }
  else      { for (int i = 0; i < 32; i += 8) outf[(size_t)(bc + ty + i) * R + br + tx] = t[tx][ty + i]; }
}

// ---------------------------------------------------------------------------
// Shared GEMM core: C128x128 tile, BK=64, 8 waves (each 32x64 = 2x4 frags).
// A [M,K] bf16 row-major, BT [N,K] bf16 row-major. 512 threads.
// LDS tile 128x64: slot s (16B) holds row s>>3, chunk (s&7)^((s>>3)&7).
__device__ __forceinline__ void gemm_core(const unsigned short* __restrict__ A,
                                          const unsigned short* __restrict__ BT,
                                          int bm0, int bn0, int K,
                                          unsigned short* As, unsigned short* Bs,
                                          float4_t acc[2][4]) {
  int tid = threadIdx.x, w = tid >> 6;
  int lane = tid & 63, quad = lane >> 4, l16 = lane & 15;
  int wm = w >> 1, wn = w & 1;                     // 4x2 wave grid, 32x64 each
  int r = tid >> 3, x = tid & 7;
  int sc = (x ^ (r & 7)) * 8;                      // swizzled source col
  for (int k0 = 0; k0 < K; k0 += 64) {
    __syncthreads();
#pragma unroll
    for (int c = 0; c < 2; ++c) {
      async16(&A [(size_t)(bm0 + c * 64 + r) * K + k0 + sc], &As[(size_t)(c * 512 + tid) * 8]);
      async16(&BT[(size_t)(bn0 + c * 64 + r) * K + k0 + sc], &Bs[(size_t)(c * 512 + tid) * 8]);
    }
    __syncthreads();
#pragma unroll
    for (int ks = 0; ks < 2; ++ks) {
      bfrag af[2], bf_[4];
#pragma unroll
      for (int i = 0; i < 2; ++i) {
        int rm = wm * 32 + i * 16 + l16;
        af[i]  = *(const bfrag*)&As[(size_t)(rm * 8 + ((ks * 4 + quad) ^ (rm & 7))) * 8];
      }
#pragma unroll
      for (int j = 0; j < 4; ++j) {
        int rn = wn * 64 + j * 16 + l16;
        bf_[j] = *(const bfrag*)&Bs[(size_t)(rn * 8 + ((ks * 4 + quad) ^ (rn & 7))) * 8];
      }
#pragma unroll
      for (int i = 0; i < 2; ++i)
#pragma unroll
        for (int j = 0; j < 4; ++j)
          acc[i][j] = MFMA_BF16(af[i], bf_[j], acc[i][j]);
    }
  }
}

// GEMM1: qkv = rope(x @ Wqkv) stored PLAIN row-major [16384][3072].
// R21: decode reverted to R19-validated A-major XCD-contiguous swz.
__global__ __launch_bounds__(512, 4) void gemm1_kernel(const unsigned short* __restrict__ xb,
    const unsigned short* __restrict__ wqkvT,
    const float* __restrict__ fcT, const float* __restrict__ fsT,
    unsigned short* __restrict__ qkv) {
  __shared__ __align__(16) unsigned char smem[34816];        // max(As|Bs 32K, Es 34.8K)
  unsigned short* As = (unsigned short*)smem;
  unsigned short* Bs = (unsigned short*)(smem + 16384);
  float4_t acc[2][4];
  for (int i = 0; i < 2; ++i) for (int j = 0; j < 4; ++j)
    acc[i][j] = (float4_t){0.f, 0.f, 0.f, 0.f};
  int lin = blockIdx.y * 24 + blockIdx.x;          // 0..3071, x-fastest
  int swz = (lin & 7) * 384 + (lin >> 3);          // XCD-contiguous bijection
  int bn0 = (swz % 24) * 128, bm0 = (swz / 24) * 128;
  gemm_core(xb, wqkvT, bm0, bn0, 1024, As, Bs, acc);

  int tid = threadIdx.x, w = tid >> 6, lane = tid & 63, quad = lane >> 4, l16 = lane & 15;
  int wm = w >> 1, wn = w & 1;

  // ---- rope in registers (R3 numerics; fcT/fsT float4 loads over r) -------
  for (int i = 0; i < 2; ++i) {
    int t0 = (bm0 + wm * 32 + i * 16 + quad * 4) & 4095;   // r spans t0..t0+3
    for (int j = 0; j < 4; ++j) {
      int gcol = bn0 + wn * 64 + j * 16 + l16;    // wave-uniform branch (16-aligned)
      if (gcol < 2048) {
        int ci = (gcol & 63) >> 1;                // pair index 0..31 (per lane)
        const float4_t c4 = *(const float4_t*)&fcT[(size_t)ci * 4096 + t0];
        const float4_t s4 = *(const float4_t*)&fsT[(size_t)ci * 4096 + t0];
        for (int r = 0; r < 4; ++r) {
          float val = acc[i][j][r];
          float partner = __shfl_xor(val, 1);     // even<->odd channel pair
          float c = c4[r], s = s4[r];             // == fc[t*32+ci], fs[t*32+ci]
          acc[i][j][r] = (gcol & 1) ? fmaf(partner, s, val * c)
                                    : fmaf(-partner, s, val * c);
        }
      }
    }
  }

  // ---- LDS restage + coalesced plain stores -------------------------------
  // Es aliases As/Bs: barrier ensures all K-loop ds_reads done; after it each
  // wave's Es slice is private (R9-validated intra-wave LDS ordering).
  __syncthreads();
  float* Es = (float*)smem;
  float* slice = &Es[w * 1088];
  for (int i = 0; i < 2; ++i) {
    for (int j = 0; j < 4; ++j)
      for (int r = 0; r < 4; ++r)
        slice[(quad * 4 + r) * 68 + j * 16 + l16] = acc[i][j][r];
    for (int m = 0; m < 2; ++m) {
      int rl = m * 8 + (lane >> 3);               // 0..15 local row
      int cb = (lane & 7) * 8;                    // 8-aligned col base
      const float* rp = &slice[rl * 68 + cb];
      ushort8 outv;
      outv[0] = f2bf(rp[0]); outv[1] = f2bf(rp[1]);
      outv[2] = f2bf(rp[2]); outv[3] = f2bf(rp[3]);
      outv[4] = f2bf(rp[4]); outv[5] = f2bf(rp[5]);
      outv[6] = f2bf(rp[6]); outv[7] = f2bf(rp[7]);
      int grow = bm0 + wm * 32 + i * 16 + rl;     // = b*4096 + t
      int gcol = bn0 + wn * 64 + cb;              // 0..3071, 8-aligned
      *(ushort8*)&qkv[(size_t)grow * 3072 + gcol] = outv;
    }
  }
}

// GEMM2: out = o @ Wo, f32 store into d_out[0 .. 16777216). R21: reverted swz.
__global__ __launch_bounds__(512, 4) void gemm2_kernel(const unsigned short* __restrict__ ob,
    const unsigned short* __restrict__ woT, float* __restrict__ outp) {
  __shared__ __align__(16) unsigned short As[128 * 64];
  __shared__ __align__(16) unsigned short Bs[128 * 64];
  float4_t acc[2][4];
  for (int i = 0; i < 2; ++i) for (int j = 0; j < 4; ++j)
    acc[i][j] = (float4_t){0.f, 0.f, 0.f, 0.f};
  int lin = blockIdx.y * 8 + blockIdx.x;           // 0..1023, x-fastest
  int swz = (lin & 7) * 128 + (lin >> 3);          // XCD-contiguous bijection
  int bn0 = (swz & 7) * 128, bm0 = (swz >> 3) * 128;
  gemm_core(ob, woT, bm0, bn0, 1024, As, Bs, acc);
  int tid = threadIdx.x, w = tid >> 6, lane = tid & 63, quad = lane >> 4, l16 = lane & 15;
  int wm = w >> 1, wn = w & 1;
  for (int i = 0; i < 2; ++i)
    for (int j = 0; j < 4; ++j)
      for (int r = 0; r < 4; ++r)
        outp[(size_t)(bm0 + wm * 32 + i * 16 + quad * 4 + r) * 1024 +
             bn0 + wn * 64 + j * 16 + l16] = acc[i][j][r];
}

// ---------------------------------------------------------------------------
// MFMA flash attention (lin<2048) + fused pools tail blocks (lin>=2048).
// attn: R13 structure (QBLK=128, 512 threads, 8 waves, 128-key tiles,
// ntiles = qt2+1) + R14 T14 async-STAGE split + R16 XCD swizzle.
// Inverse scramble map (R12-validated):
//   q/k row 'row': t = ((row&255)<<4)|h, col = (2g+(row>>8))*64 + hs (+1024 k)
//   v   row 'row': t = g*512+row,        col = 2048 + h*64 + hs
__global__ __launch_bounds__(512) void attn_kernel(const unsigned short* __restrict__ qkv,
    unsigned short* __restrict__ ob,
    const float* __restrict__ qp, const float* __restrict__ kp,
    const float* __restrict__ vp, float* __restrict__ outp) {
  __shared__ __align__(16) unsigned short Ks[128 * 64];      // 1024 swizzled 16B slots
  __shared__ __align__(16) unsigned short VTs[64 * 136];     // [hs][key 0..127], pad->136
  __shared__ __align__(16) unsigned short Ps[8 * 16 * 136];  // per-wave P[16 q][128 k]
  int lin = blockIdx.x;                            // 0..2495
  int tid = threadIdx.x;

  if (lin >= 2048) {               // ---- pooled qb/kb/vb (tail-fill blocks)
    float* red = (float*)Ks;       // 3*8*64 f32 = 6KB scratch in Ks
    int pid = lin - 2048;          // 0..447
    int g = pid % 7, h = (pid / 7) % 16, b = pid / 112;
    int hs = tid & 63, tc = tid >> 6;              // 8 chunks x 64 t
    const unsigned short* qb_ = qkv + ((size_t)b * 4096 + h) * 3072 + g * 128 + hs;
    const unsigned short* vb_ = qkv + ((size_t)(b * 4096 + g * 512)) * 3072 + 2048 + h * 64 + hs;
    float aq = 0.f, ak = 0.f, av = 0.f;
    for (int t = tc * 64; t < tc * 64 + 64; ++t) {
      size_t qoff = ((size_t)((t & 255) << 4)) * 3072 + (t >> 8) * 64;
      aq = fmaf(bf2f(qb_[qoff]), qp[t], aq);
      ak = fmaf(bf2f(qb_[qoff + 1024]), kp[t], ak);
      av = fmaf(bf2f(vb_[(size_t)t * 3072]), vp[t], av);
    }
    red[(0 * 8 + tc) * 64 + hs] = aq;
    red[(1 * 8 + tc) * 64 + hs] = ak;
    red[(2 * 8 + tc) * 64 + hs] = av;
    __syncthreads();
    if (tc < 3) {                                  // tc: 0=q 1=k 2=v
      float a = 0.f;
      for (int c = 0; c < 8; ++c) a += red[(tc * 8 + c) * 64 + hs];
      size_t oi = (((size_t)b * 16 + h) * 7 + g) * 64 + hs;
      size_t off = (tc == 0) ? 0 : (tc == 1) ? 28672 : 57344;
      outp[16777216 + off + oi] = a;
    }
    return;
  }

  int bx = (lin & 7) * 256 + (lin >> 3);           // XCD-contiguous bijection
  int qt2 = bx & 3, g = (bx >> 2) & 7, h = (bx >> 5) & 15, b = bx >> 9;
  int w = tid >> 6, lane = tid & 63, quad = lane >> 4, l16 = lane & 15;

  const unsigned short* QKb = qkv + ((size_t)b * 4096 + h) * 3072 + g * 128;
  const unsigned short* Vb  = qkv + ((size_t)(b * 4096 + g * 512)) * 3072 + 2048 + h * 64;

  int qrow = qt2 * 128 + w * 16 + l16;
  const unsigned short* Qr = QKb + ((size_t)((qrow & 255) << 4)) * 3072 + (qrow >> 8) * 64;
  bfrag qf0 = *(const bfrag*)&Qr[quad * 8];
  bfrag qf1 = *(const bfrag*)&Qr[32 + quad * 8];

  float4_t acc[4];
#pragma unroll
  for (int i = 0; i < 4; ++i) acc[i] = (float4_t){0.f, 0.f, 0.f, 0.f};
  float m_i[4] = {-1e30f, -1e30f, -1e30f, -1e30f};
  float l_i[4] = {0.f, 0.f, 0.f, 0.f};

  int skey = tid >> 3, sx = tid & 7, ss = sx ^ (skey & 7);   // K staging swizzle
  int kp2 = tid & 63, hsg = tid >> 6;                         // V staging split (8 hs each)
  unsigned short* Pw = &Ps[w * 2176];                         // 16*136
  int ntiles = qt2 + 1;

  ushort8 kreg0, kreg1, vreg0, vreg1;

  // prologue: load + write tile 0
  {
    int krow0 = skey, krow1 = 64 + skey;
    kreg0 = *(const ushort8*)&QKb[((size_t)((krow0 & 255) << 4)) * 3072 + (krow0 >> 8) * 64 + 1024 + ss * 8];
    kreg1 = *(const ushort8*)&QKb[((size_t)((krow1 & 255) << 4)) * 3072 + (krow1 >> 8) * 64 + 1024 + ss * 8];
    const unsigned short* vp0 = Vb + (size_t)(kp2 * 2) * 3072 + hsg * 8;
    vreg0 = *(const ushort8*)vp0;
    vreg1 = *(const ushort8*)(vp0 + 3072);
    *(ushort8*)&Ks[(size_t)(tid) * 8]       = kreg0;
    *(ushort8*)&Ks[(size_t)(512 + tid) * 8] = kreg1;
#pragma unroll
    for (int e = 0; e < 8; ++e)
      *(unsigned*)&VTs[(size_t)(hsg * 8 + e) * 136 + kp2 * 2] =
          (unsigned)vreg0[e] | ((unsigned)vreg1[e] << 16);
  }

  for (int kt = 0; kt < ntiles; ++kt) {
    __syncthreads();   // staged LDS writes for tile kt visible to all waves

    // ---- QK^T (reads Ks) ----
    float4_t s[8];
#pragma unroll
    for (int c = 0; c < 8; ++c) s[c] = (float4_t){0.f, 0.f, 0.f, 0.f};
    {
      int sl0 = l16 * 8 + (quad ^ (l16 & 7));          // hs 0..31, key l16+16c
      int sl1 = l16 * 8 + ((4 + quad) ^ (l16 & 7));    // hs 32..63
#pragma unroll
      for (int c = 0; c < 8; ++c) {
        s[c] = MFMA_BF16(qf0, *(const bfrag*)&Ks[(size_t)(sl0 + 128 * c) * 8], s[c]);
        s[c] = MFMA_BF16(qf1, *(const bfrag*)&Ks[(size_t)(sl1 + 128 * c) * 8], s[c]);
      }
    }

    // ---- issue next tile's global loads (latency hides under softmax+PV) --
    bool more = (kt + 1 < ntiles);
    if (more) {
      int kb = (kt + 1) * 128;
      int krow0 = kb + skey, krow1 = kb + 64 + skey;
      kreg0 = *(const ushort8*)&QKb[((size_t)((krow0 & 255) << 4)) * 3072 + (krow0 >> 8) * 64 + 1024 + ss * 8];
      kreg1 = *(const ushort8*)&QKb[((size_t)((krow1 & 255) << 4)) * 3072 + (krow1 >> 8) * 64 + 1024 + ss * 8];
      const unsigned short* vp0 = Vb + (size_t)(kb + kp2 * 2) * 3072 + hsg * 8;
      vreg0 = *(const ushort8*)vp0;
      vreg1 = *(const ushort8*)(vp0 + 3072);
    }

    // ---- online softmax ----
    int qa = qt2 * 128 + w * 16 + quad * 4;
    int kb0 = kt * 128 + l16;
#pragma unroll
    for (int r = 0; r < 4; ++r) {
      float vv[8];
#pragma unroll
      for (int c = 0; c < 8; ++c) {
        vv[c] = s[c][r] * 0.125f;
        if (kb0 + 16 * c > qa + r) vv[c] = -1e30f;
      }
      float tm = fmaxf(fmaxf(fmaxf(vv[0], vv[1]), fmaxf(vv[2], vv[3])),
                       fmaxf(fmaxf(vv[4], vv[5]), fmaxf(vv[6], vv[7])));
      tm = fmaxf(tm, __shfl_xor(tm, 1));
      tm = fmaxf(tm, __shfl_xor(tm, 2));
      tm = fmaxf(tm, __shfl_xor(tm, 4));
      tm = fmaxf(tm, __shfl_xor(tm, 8));
      float nm = fmaxf(m_i[r], tm);
      float alpha = __expf(m_i[r] - nm);
      m_i[r] = nm;
      float p[8], rs = 0.f;
#pragma unroll
      for (int c = 0; c < 8; ++c) { p[c] = __expf(vv[c] - nm); rs += p[c]; }
      rs += __shfl_xor(rs, 1);
      rs += __shfl_xor(rs, 2);
      rs += __shfl_xor(rs, 4);
      rs += __shfl_xor(rs, 8);
      l_i[r] = l_i[r] * alpha + rs;
      acc[0][r] *= alpha; acc[1][r] *= alpha; acc[2][r] *= alpha; acc[3][r] *= alpha;
      int pr = (quad * 4 + r) * 136 + l16;
#pragma unroll
      for (int c = 0; c < 8; ++c) Pw[pr + 16 * c] = f2bf(p[c]);
    }
    // No barrier: Pw is this wave's private slice; intra-wave LDS write->read
    // ordering is architectural (lgkmcnt).
    bfrag pf[4];
#pragma unroll
    for (int c = 0; c < 4; ++c)
      pf[c] = *(const bfrag*)&Pw[(size_t)l16 * 136 + 32 * c + quad * 8];
#pragma unroll
    for (int ht = 0; ht < 4; ++ht) {
#pragma unroll
      for (int c = 0; c < 4; ++c) {
        bfrag vf = *(const bfrag*)&VTs[(size_t)(ht * 16 + l16) * 136 + 32 * c + quad * 8];
        acc[ht] = MFMA_BF16(pf[c], vf, acc[ht]);
      }
    }

    __syncthreads();   // all LDS reads of tile kt complete
    if (more) {        // write tile kt+1 (visible after loop-top barrier)
      *(ushort8*)&Ks[(size_t)(tid) * 8]       = kreg0;
      *(ushort8*)&Ks[(size_t)(512 + tid) * 8] = kreg1;
#pragma unroll
      for (int e = 0; e < 8; ++e)
        *(unsigned*)&VTs[(size_t)(hsg * 8 + e) * 136 + kp2 * 2] =
            (unsigned)vreg0[e] | ((unsigned)vreg1[e] << 16);
    }
  }

  // o_final[b, g*512+gt, h*64+hs]
  int orow = b * 4096 + g * 512 + qt2 * 128 + w * 16 + quad * 4;
#pragma unroll
  for (int ht = 0; ht < 4; ++ht)
#pragma unroll
    for (int r = 0; r < 4; ++r)
      ob[(size_t)(orow + r) * 1024 + h * 64 + ht * 16 + l16] = f2bf(acc[ht][r] / l_i[r]);
}

// ---------------------------------------------------------------------------
extern "C" void kernel_launch(void* const* d_in, const int* in_sizes, int n_in,
                              void* d_out, int out_size, void* d_ws, size_t ws_size,
                              hipStream_t stream) {
  (void)in_sizes; (void)n_in; (void)out_size; (void)ws_size;
  const float* x    = (const float*)d_in[0];
  const float* Wqkv = (const float*)d_in[1];
  const float* Wo   = (const float*)d_in[2];
  const float* qp   = (const float*)d_in[3];
  const float* kp   = (const float*)d_in[4];
  const float* vp   = (const float*)d_in[5];
  const float* fc   = (const float*)d_in[6];
  const float* fs   = (const float*)d_in[7];
  float* outp = (float*)d_out;                     // f32 output (reference dtype)

  char* ws = (char*)d_ws;                          // 142.6 MiB used
  unsigned short* xb    = (unsigned short*)(ws);               // 33.5MB (o aliases it later)
  unsigned short* wqkvT = (unsigned short*)(ws + 33554432);    // 6.3MB
  unsigned short* woT   = (unsigned short*)(ws + 39845888);    // 2.1MB
  unsigned short* qkv   = (unsigned short*)(ws + 41943040);    // 100.7MB [16384][3072]
  unsigned short* ob    = xb;  // safe alias: xb fully consumed by gemm1 before attn writes

  // fcT/fsT scratch lives in d_out[0 .. 512K floats): dead until gemm2, which
  // runs LAST and overwrites it. 32x4096 f32 each.
  float* fcT = outp;
  float* fsT = outp + 131072;

  prep_kernel<<<12544, dim3(32, 8), 0, stream>>>(x, xb, Wqkv, wqkvT, Wo, woT,
                                                 fc, fs, fcT, fsT);
  gemm1_kernel<<<dim3(24, 128), 512, 0, stream>>>(xb, wqkvT, fcT, fsT, qkv);
  attn_kernel<<<2496, 512, 0, stream>>>(qkv, ob, qp, kp, vp, outp);
  gemm2_kernel<<<dim3(8, 128), 512, 0, stream>>>(ob, woT, outp);
}

// Round 16
// 402.297 us; speedup vs baseline: 1.1195x; 1.1178x over previous
//
#include <hip/hip_runtime.h>

// ---------------------------------------------------------------------------
// CausalSelfAttention2: x@Wqkv -> rope -> 512x block-causal attn -> o@Wo ;
// plus learned time-pooled qb/kb/vb outputs.
// Sizes: B=4 T=4096 C=1024 H=16 G=8 HS=64 GT=512. d_out is FLOAT32.
// R22: UN-FUSE pools. R21 proved bn-major was innocent (revert changed
// nothing); the R20 regression was the fusions. Fused pools tail blocks
// inherited attn's 68.6KB LDS + 512-thread shape -> 2 blocks/CU for a
// latency-bound stride-3072 gather with HALF the old TLP. pools restored to
// its validated standalone form (1024 thr, 12KB LDS, 16x32 chunks); attn
// back to pure 2048-block grid (R19-identical). prep fusion KEPT as the
// last isolated variable vs R19 (if total ~411-420 it is neutral; if >=435
// it gets reverted next).
// R19 8-wave 32x64 GEMM core, R16 XCD swz, R15 BK=64, R13/R14 attn.
// ---------------------------------------------------------------------------

typedef float  float4_t  __attribute__((ext_vector_type(4)));
typedef short  bfrag     __attribute__((ext_vector_type(8)));   // 8 bf16
typedef unsigned short ushort8 __attribute__((ext_vector_type(8)));

#define MFMA_BF16(A, B, C) __builtin_amdgcn_mfma_f32_16x16x32_bf16((A), (B), (C), 0, 0, 0)

__device__ __forceinline__ unsigned short f2bf(float f) {
  union { float f; unsigned u; } v; v.f = f;
  return (unsigned short)((v.u + 0x7FFFu + ((v.u >> 16) & 1u)) >> 16);   // RNE
}
__device__ __forceinline__ float bf2f(unsigned short h) {
  union { unsigned u; float f; } v; v.u = ((unsigned)h) << 16; return v.f;
}
// async global->LDS, 16B per lane; LDS dest = wave-uniform base + lane*16
__device__ __forceinline__ void async16(const void* g, void* l) {
  __builtin_amdgcn_global_load_lds(
      (const __attribute__((address_space(1))) unsigned int*)(unsigned long long)g,
      (__attribute__((address_space(3))) unsigned int*)(unsigned long long)l,
      16, 0, 0);
}

// ---------------------------------------------------------------------------
// prep: [0,8192) cvt x->xb ; [8192,11264) Wqkv^T ; [11264,12288) Wo^T ;
//       [12288,12544) fc/fs f32 transpose. 256 thr as (32,8).
__global__ __launch_bounds__(256) void prep_kernel(
    const float* __restrict__ x, unsigned short* __restrict__ xb,
    const float* __restrict__ Wqkv, unsigned short* __restrict__ wqkvT,
    const float* __restrict__ Wo, unsigned short* __restrict__ woT,
    const float* __restrict__ fc, const float* __restrict__ fs,
    float* __restrict__ fcT, float* __restrict__ fsT) {
  int idx = blockIdx.x;
  int tx = threadIdx.x, ty = threadIdx.y;
  int tid = ty * 32 + tx;
  if (idx < 8192) {                       // ---- cvt: 8 f32 -> 8 bf16 / thread
    int i = idx * 256 + tid;
    const float4_t* p = (const float4_t*)x + (size_t)i * 2;
    float4_t a = p[0], c = p[1];
    ushort8 r;
    r[0] = f2bf(a[0]); r[1] = f2bf(a[1]); r[2] = f2bf(a[2]); r[3] = f2bf(a[3]);
    r[4] = f2bf(c[0]); r[5] = f2bf(c[1]); r[6] = f2bf(c[2]); r[7] = f2bf(c[3]);
    *((ushort8*)xb + i) = r;
    return;
  }
  __shared__ float t[32][33];
  const float* in; float* outf = nullptr; unsigned short* outh = nullptr;
  int R, C, bx, by;
  if (idx < 11264)      { int k = idx - 8192;  in = Wqkv; outh = wqkvT; R = 1024; C = 3072; bx = k % 96; by = k / 96; }
  else if (idx < 12288) { int k = idx - 11264; in = Wo;   outh = woT;   R = 1024; C = 1024; bx = k % 32; by = k / 32; }
  else                  { int k = idx - 12288; in = (k >= 128) ? fs : fc; outf = (k >= 128) ? fsT : fcT;
                          R = 4096; C = 32; bx = 0; by = k & 127; }
  int bc = bx * 32, br = by * 32;
  for (int i = 0; i < 32; i += 8) t[ty + i][tx] = in[(size_t)(br + ty + i) * C + bc + tx];
  __syncthreads();
  if (outh) { for (int i = 0; i < 32; i += 8) outh[(size_t)(bc + ty + i) * R + br + tx] = f2bf(t[tx][ty + i]); }
  else      { for (int i = 0; i < 32; i += 8) outf[(size_t)(bc + ty + i) * R + br + tx] = t[tx][ty + i]; }
}

// ---------------------------------------------------------------------------
// Shared GEMM core: C128x128 tile, BK=64, 8 waves (each 32x64 = 2x4 frags).
// A [M,K] bf16 row-major, BT [N,K] bf16 row-major. 512 threads.
// LDS tile 128x64: slot s (16B) holds row s>>3, chunk (s&7)^((s>>3)&7).
__device__ __forceinline__ void gemm_core(const unsigned short* __restrict__ A,
                                          const unsigned short* __restrict__ BT,
                                          int bm0, int bn0, int K,
                                          unsigned short* As, unsigned short* Bs,
                                          float4_t acc[2][4]) {
  int tid = threadIdx.x, w = tid >> 6;
  int lane = tid & 63, quad = lane >> 4, l16 = lane & 15;
  int wm = w >> 1, wn = w & 1;                     // 4x2 wave grid, 32x64 each
  int r = tid >> 3, x = tid & 7;
  int sc = (x ^ (r & 7)) * 8;                      // swizzled source col
  for (int k0 = 0; k0 < K; k0 += 64) {
    __syncthreads();
#pragma unroll
    for (int c = 0; c < 2; ++c) {
      async16(&A [(size_t)(bm0 + c * 64 + r) * K + k0 + sc], &As[(size_t)(c * 512 + tid) * 8]);
      async16(&BT[(size_t)(bn0 + c * 64 + r) * K + k0 + sc], &Bs[(size_t)(c * 512 + tid) * 8]);
    }
    __syncthreads();
#pragma unroll
    for (int ks = 0; ks < 2; ++ks) {
      bfrag af[2], bf_[4];
#pragma unroll
      for (int i = 0; i < 2; ++i) {
        int rm = wm * 32 + i * 16 + l16;
        af[i]  = *(const bfrag*)&As[(size_t)(rm * 8 + ((ks * 4 + quad) ^ (rm & 7))) * 8];
      }
#pragma unroll
      for (int j = 0; j < 4; ++j) {
        int rn = wn * 64 + j * 16 + l16;
        bf_[j] = *(const bfrag*)&Bs[(size_t)(rn * 8 + ((ks * 4 + quad) ^ (rn & 7))) * 8];
      }
#pragma unroll
      for (int i = 0; i < 2; ++i)
#pragma unroll
        for (int j = 0; j < 4; ++j)
          acc[i][j] = MFMA_BF16(af[i], bf_[j], acc[i][j]);
    }
  }
}

// GEMM1: qkv = rope(x @ Wqkv) stored PLAIN row-major [16384][3072].
__global__ __launch_bounds__(512, 4) void gemm1_kernel(const unsigned short* __restrict__ xb,
    const unsigned short* __restrict__ wqkvT,
    const float* __restrict__ fcT, const float* __restrict__ fsT,
    unsigned short* __restrict__ qkv) {
  __shared__ __align__(16) unsigned char smem[34816];        // max(As|Bs 32K, Es 34.8K)
  unsigned short* As = (unsigned short*)smem;
  unsigned short* Bs = (unsigned short*)(smem + 16384);
  float4_t acc[2][4];
  for (int i = 0; i < 2; ++i) for (int j = 0; j < 4; ++j)
    acc[i][j] = (float4_t){0.f, 0.f, 0.f, 0.f};
  int lin = blockIdx.y * 24 + blockIdx.x;          // 0..3071, x-fastest
  int swz = (lin & 7) * 384 + (lin >> 3);          // XCD-contiguous bijection
  int bn0 = (swz % 24) * 128, bm0 = (swz / 24) * 128;
  gemm_core(xb, wqkvT, bm0, bn0, 1024, As, Bs, acc);

  int tid = threadIdx.x, w = tid >> 6, lane = tid & 63, quad = lane >> 4, l16 = lane & 15;
  int wm = w >> 1, wn = w & 1;

  // ---- rope in registers (R3 numerics; fcT/fsT float4 loads over r) -------
  for (int i = 0; i < 2; ++i) {
    int t0 = (bm0 + wm * 32 + i * 16 + quad * 4) & 4095;   // r spans t0..t0+3
    for (int j = 0; j < 4; ++j) {
      int gcol = bn0 + wn * 64 + j * 16 + l16;    // wave-uniform branch (16-aligned)
      if (gcol < 2048) {
        int ci = (gcol & 63) >> 1;                // pair index 0..31 (per lane)
        const float4_t c4 = *(const float4_t*)&fcT[(size_t)ci * 4096 + t0];
        const float4_t s4 = *(const float4_t*)&fsT[(size_t)ci * 4096 + t0];
        for (int r = 0; r < 4; ++r) {
          float val = acc[i][j][r];
          float partner = __shfl_xor(val, 1);     // even<->odd channel pair
          float c = c4[r], s = s4[r];             // == fc[t*32+ci], fs[t*32+ci]
          acc[i][j][r] = (gcol & 1) ? fmaf(partner, s, val * c)
                                    : fmaf(-partner, s, val * c);
        }
      }
    }
  }

  // ---- LDS restage + coalesced plain stores -------------------------------
  // Es aliases As/Bs: barrier ensures all K-loop ds_reads done; after it each
  // wave's Es slice is private (R9-validated intra-wave LDS ordering).
  __syncthreads();
  float* Es = (float*)smem;
  float* slice = &Es[w * 1088];
  for (int i = 0; i < 2; ++i) {
    for (int j = 0; j < 4; ++j)
      for (int r = 0; r < 4; ++r)
        slice[(quad * 4 + r) * 68 + j * 16 + l16] = acc[i][j][r];
    for (int m = 0; m < 2; ++m) {
      int rl = m * 8 + (lane >> 3);               // 0..15 local row
      int cb = (lane & 7) * 8;                    // 8-aligned col base
      const float* rp = &slice[rl * 68 + cb];
      ushort8 outv;
      outv[0] = f2bf(rp[0]); outv[1] = f2bf(rp[1]);
      outv[2] = f2bf(rp[2]); outv[3] = f2bf(rp[3]);
      outv[4] = f2bf(rp[4]); outv[5] = f2bf(rp[5]);
      outv[6] = f2bf(rp[6]); outv[7] = f2bf(rp[7]);
      int grow = bm0 + wm * 32 + i * 16 + rl;     // = b*4096 + t
      int gcol = bn0 + wn * 64 + cb;              // 0..3071, 8-aligned
      *(ushort8*)&qkv[(size_t)grow * 3072 + gcol] = outv;
    }
  }
}

// GEMM2: out = o @ Wo, f32 store into d_out[0 .. 16777216).
__global__ __launch_bounds__(512, 4) void gemm2_kernel(const unsigned short* __restrict__ ob,
    const unsigned short* __restrict__ woT, float* __restrict__ outp) {
  __shared__ __align__(16) unsigned short As[128 * 64];
  __shared__ __align__(16) unsigned short Bs[128 * 64];
  float4_t acc[2][4];
  for (int i = 0; i < 2; ++i) for (int j = 0; j < 4; ++j)
    acc[i][j] = (float4_t){0.f, 0.f, 0.f, 0.f};
  int lin = blockIdx.y * 8 + blockIdx.x;           // 0..1023, x-fastest
  int swz = (lin & 7) * 128 + (lin >> 3);          // XCD-contiguous bijection
  int bn0 = (swz & 7) * 128, bm0 = (swz >> 3) * 128;
  gemm_core(ob, woT, bm0, bn0, 1024, As, Bs, acc);
  int tid = threadIdx.x, w = tid >> 6, lane = tid & 63, quad = lane >> 4, l16 = lane & 15;
  int wm = w >> 1, wn = w & 1;
  for (int i = 0; i < 2; ++i)
    for (int j = 0; j < 4; ++j)
      for (int r = 0; r < 4; ++r)
        outp[(size_t)(bm0 + wm * 32 + i * 16 + quad * 4 + r) * 1024 +
             bn0 + wn * 64 + j * 16 + l16] = acc[i][j][r];
}

// ---------------------------------------------------------------------------
// MFMA flash attention, pure 2048-block grid (R19-identical).
// R13 structure (QBLK=128, 512 threads, 8 waves, 128-key tiles,
// ntiles = qt2+1) + R14 T14 async-STAGE split + R16 XCD swizzle.
// Inverse scramble map (R12-validated):
//   q/k row 'row': t = ((row&255)<<4)|h, col = (2g+(row>>8))*64 + hs (+1024 k)
//   v   row 'row': t = g*512+row,        col = 2048 + h*64 + hs
__global__ __launch_bounds__(512) void attn_kernel(const unsigned short* __restrict__ qkv,
    unsigned short* __restrict__ ob) {
  __shared__ __align__(16) unsigned short Ks[128 * 64];      // 1024 swizzled 16B slots
  __shared__ __align__(16) unsigned short VTs[64 * 136];     // [hs][key 0..127], pad->136
  __shared__ __align__(16) unsigned short Ps[8 * 16 * 136];  // per-wave P[16 q][128 k]
  int lin = blockIdx.x;                            // 0..2047
  int bx = (lin & 7) * 256 + (lin >> 3);           // XCD-contiguous bijection
  int qt2 = bx & 3, g = (bx >> 2) & 7, h = (bx >> 5) & 15, b = bx >> 9;
  int tid = threadIdx.x, w = tid >> 6, lane = tid & 63, quad = lane >> 4, l16 = lane & 15;

  const unsigned short* QKb = qkv + ((size_t)b * 4096 + h) * 3072 + g * 128;
  const unsigned short* Vb  = qkv + ((size_t)(b * 4096 + g * 512)) * 3072 + 2048 + h * 64;

  int qrow = qt2 * 128 + w * 16 + l16;
  const unsigned short* Qr = QKb + ((size_t)((qrow & 255) << 4)) * 3072 + (qrow >> 8) * 64;
  bfrag qf0 = *(const bfrag*)&Qr[quad * 8];
  bfrag qf1 = *(const bfrag*)&Qr[32 + quad * 8];

  float4_t acc[4];
#pragma unroll
  for (int i = 0; i < 4; ++i) acc[i] = (float4_t){0.f, 0.f, 0.f, 0.f};
  float m_i[4] = {-1e30f, -1e30f, -1e30f, -1e30f};
  float l_i[4] = {0.f, 0.f, 0.f, 0.f};

  int skey = tid >> 3, sx = tid & 7, ss = sx ^ (skey & 7);   // K staging swizzle
  int kp2 = tid & 63, hsg = tid >> 6;                         // V staging split (8 hs each)
  unsigned short* Pw = &Ps[w * 2176];                         // 16*136
  int ntiles = qt2 + 1;

  ushort8 kreg0, kreg1, vreg0, vreg1;

  // prologue: load + write tile 0
  {
    int krow0 = skey, krow1 = 64 + skey;
    kreg0 = *(const ushort8*)&QKb[((size_t)((krow0 & 255) << 4)) * 3072 + (krow0 >> 8) * 64 + 1024 + ss * 8];
    kreg1 = *(const ushort8*)&QKb[((size_t)((krow1 & 255) << 4)) * 3072 + (krow1 >> 8) * 64 + 1024 + ss * 8];
    const unsigned short* vp0 = Vb + (size_t)(kp2 * 2) * 3072 + hsg * 8;
    vreg0 = *(const ushort8*)vp0;
    vreg1 = *(const ushort8*)(vp0 + 3072);
    *(ushort8*)&Ks[(size_t)(tid) * 8]       = kreg0;
    *(ushort8*)&Ks[(size_t)(512 + tid) * 8] = kreg1;
#pragma unroll
    for (int e = 0; e < 8; ++e)
      *(unsigned*)&VTs[(size_t)(hsg * 8 + e) * 136 + kp2 * 2] =
          (unsigned)vreg0[e] | ((unsigned)vreg1[e] << 16);
  }

  for (int kt = 0; kt < ntiles; ++kt) {
    __syncthreads();   // staged LDS writes for tile kt visible to all waves

    // ---- QK^T (reads Ks) ----
    float4_t s[8];
#pragma unroll
    for (int c = 0; c < 8; ++c) s[c] = (float4_t){0.f, 0.f, 0.f, 0.f};
    {
      int sl0 = l16 * 8 + (quad ^ (l16 & 7));          // hs 0..31, key l16+16c
      int sl1 = l16 * 8 + ((4 + quad) ^ (l16 & 7));    // hs 32..63
#pragma unroll
      for (int c = 0; c < 8; ++c) {
        s[c] = MFMA_BF16(qf0, *(const bfrag*)&Ks[(size_t)(sl0 + 128 * c) * 8], s[c]);
        s[c] = MFMA_BF16(qf1, *(const bfrag*)&Ks[(size_t)(sl1 + 128 * c) * 8], s[c]);
      }
    }

    // ---- issue next tile's global loads (latency hides under softmax+PV) --
    bool more = (kt + 1 < ntiles);
    if (more) {
      int kb = (kt + 1) * 128;
      int krow0 = kb + skey, krow1 = kb + 64 + skey;
      kreg0 = *(const ushort8*)&QKb[((size_t)((krow0 & 255) << 4)) * 3072 + (krow0 >> 8) * 64 + 1024 + ss * 8];
      kreg1 = *(const ushort8*)&QKb[((size_t)((krow1 & 255) << 4)) * 3072 + (krow1 >> 8) * 64 + 1024 + ss * 8];
      const unsigned short* vp0 = Vb + (size_t)(kb + kp2 * 2) * 3072 + hsg * 8;
      vreg0 = *(const ushort8*)vp0;
      vreg1 = *(const ushort8*)(vp0 + 3072);
    }

    // ---- online softmax ----
    int qa = qt2 * 128 + w * 16 + quad * 4;
    int kb0 = kt * 128 + l16;
#pragma unroll
    for (int r = 0; r < 4; ++r) {
      float vv[8];
#pragma unroll
      for (int c = 0; c < 8; ++c) {
        vv[c] = s[c][r] * 0.125f;
        if (kb0 + 16 * c > qa + r) vv[c] = -1e30f;
      }
      float tm = fmaxf(fmaxf(fmaxf(vv[0], vv[1]), fmaxf(vv[2], vv[3])),
                       fmaxf(fmaxf(vv[4], vv[5]), fmaxf(vv[6], vv[7])));
      tm = fmaxf(tm, __shfl_xor(tm, 1));
      tm = fmaxf(tm, __shfl_xor(tm, 2));
      tm = fmaxf(tm, __shfl_xor(tm, 4));
      tm = fmaxf(tm, __shfl_xor(tm, 8));
      float nm = fmaxf(m_i[r], tm);
      float alpha = __expf(m_i[r] - nm);
      m_i[r] = nm;
      float p[8], rs = 0.f;
#pragma unroll
      for (int c = 0; c < 8; ++c) { p[c] = __expf(vv[c] - nm); rs += p[c]; }
      rs += __shfl_xor(rs, 1);
      rs += __shfl_xor(rs, 2);
      rs += __shfl_xor(rs, 4);
      rs += __shfl_xor(rs, 8);
      l_i[r] = l_i[r] * alpha + rs;
      acc[0][r] *= alpha; acc[1][r] *= alpha; acc[2][r] *= alpha; acc[3][r] *= alpha;
      int pr = (quad * 4 + r) * 136 + l16;
#pragma unroll
      for (int c = 0; c < 8; ++c) Pw[pr + 16 * c] = f2bf(p[c]);
    }
    // No barrier: Pw is this wave's private slice; intra-wave LDS write->read
    // ordering is architectural (lgkmcnt).
    bfrag pf[4];
#pragma unroll
    for (int c = 0; c < 4; ++c)
      pf[c] = *(const bfrag*)&Pw[(size_t)l16 * 136 + 32 * c + quad * 8];
#pragma unroll
    for (int ht = 0; ht < 4; ++ht) {
#pragma unroll
      for (int c = 0; c < 4; ++c) {
        bfrag vf = *(const bfrag*)&VTs[(size_t)(ht * 16 + l16) * 136 + 32 * c + quad * 8];
        acc[ht] = MFMA_BF16(pf[c], vf, acc[ht]);
      }
    }

    __syncthreads();   // all LDS reads of tile kt complete
    if (more) {        // write tile kt+1 (visible after loop-top barrier)
      *(ushort8*)&Ks[(size_t)(tid) * 8]       = kreg0;
      *(ushort8*)&Ks[(size_t)(512 + tid) * 8] = kreg1;
#pragma unroll
      for (int e = 0; e < 8; ++e)
        *(unsigned*)&VTs[(size_t)(hsg * 8 + e) * 136 + kp2 * 2] =
            (unsigned)vreg0[e] | ((unsigned)vreg1[e] << 16);
    }
  }

  // o_final[b, g*512+gt, h*64+hs]
  int orow = b * 4096 + g * 512 + qt2 * 128 + w * 16 + quad * 4;
#pragma unroll
  for (int ht = 0; ht < 4; ++ht)
#pragma unroll
    for (int r = 0; r < 4; ++r)
      ob[(size_t)(orow + r) * 1024 + h * 64 + ht * 16 + l16] = f2bf(acc[ht][r] / l_i[r]);
}

// ---------------------------------------------------------------------------
// qb/kb/vb: weighted sums over gt (causal_attn on 1x1 == identity => vb pooled)
// STANDALONE again (R8/R19-validated shape): 1024 threads, 12KB LDS,
// 16 chunks x 32 t; reads plain qkv via the inverse scramble map.
__global__ __launch_bounds__(1024) void pools_kernel(const unsigned short* __restrict__ qkv,
    const float* __restrict__ qp, const float* __restrict__ kp,
    const float* __restrict__ vp, float* __restrict__ outp) {
  __shared__ float red[3][16][64];
  int g = blockIdx.x, h = blockIdx.y, b = blockIdx.z;
  int hs = threadIdx.x & 63, tc = threadIdx.x >> 6;      // 16 chunks x 32 t
  const unsigned short* qb_ = qkv + ((size_t)b * 4096 + h) * 3072 + g * 128 + hs;
  const unsigned short* vb_ = qkv + ((size_t)(b * 4096 + g * 512)) * 3072 + 2048 + h * 64 + hs;
  float aq = 0.f, ak = 0.f, av = 0.f;
  int t0 = tc * 32;
  for (int t = t0; t < t0 + 32; ++t) {
    size_t qoff = ((size_t)((t & 255) << 4)) * 3072 + (t >> 8) * 64;
    aq = fmaf(bf2f(qb_[qoff]), qp[t], aq);
    ak = fmaf(bf2f(qb_[qoff + 1024]), kp[t], ak);
    av = fmaf(bf2f(vb_[(size_t)t * 3072]), vp[t], av);
  }
  red[0][tc][hs] = aq;
  red[1][tc][hs] = ak;
  red[2][tc][hs] = av;
  __syncthreads();
  if (tc < 3) {                                          // tc: 0=q 1=k 2=v
    float a = 0.f;
    for (int c = 0; c < 16; ++c) a += red[tc][c][hs];
    size_t oi = (((size_t)b * 16 + h) * 7 + g) * 64 + hs;
    size_t off = (tc == 0) ? 0 : (tc == 1) ? 28672 : 57344;
    outp[16777216 + off + oi] = a;
  }
}

// ---------------------------------------------------------------------------
extern "C" void kernel_launch(void* const* d_in, const int* in_sizes, int n_in,
                              void* d_out, int out_size, void* d_ws, size_t ws_size,
                              hipStream_t stream) {
  (void)in_sizes; (void)n_in; (void)out_size; (void)ws_size;
  const float* x    = (const float*)d_in[0];
  const float* Wqkv = (const float*)d_in[1];
  const float* Wo   = (const float*)d_in[2];
  const float* qp   = (const float*)d_in[3];
  const float* kp   = (const float*)d_in[4];
  const float* vp   = (const float*)d_in[5];
  const float* fc   = (const float*)d_in[6];
  const float* fs   = (const float*)d_in[7];
  float* outp = (float*)d_out;                     // f32 output (reference dtype)

  char* ws = (char*)d_ws;                          // 142.6 MiB used
  unsigned short* xb    = (unsigned short*)(ws);               // 33.5MB (o aliases it later)
  unsigned short* wqkvT = (unsigned short*)(ws + 33554432);    // 6.3MB
  unsigned short* woT   = (unsigned short*)(ws + 39845888);    // 2.1MB
  unsigned short* qkv   = (unsigned short*)(ws + 41943040);    // 100.7MB [16384][3072]
  unsigned short* ob    = xb;  // safe alias: xb fully consumed by gemm1 before attn writes

  // fcT/fsT scratch lives in d_out[0 .. 512K floats): dead until gemm2, which
  // runs LAST and overwrites it. 32x4096 f32 each.
  float* fcT = outp;
  float* fsT = outp + 131072;

  prep_kernel<<<12544, dim3(32, 8), 0, stream>>>(x, xb, Wqkv, wqkvT, Wo, woT,
                                                 fc, fs, fcT, fsT);
  gemm1_kernel<<<dim3(24, 128), 512, 0, stream>>>(xb, wqkvT, fcT, fsT, qkv);
  attn_kernel<<<2048, 512, 0, stream>>>(qkv, ob);
  pools_kernel<<<dim3(7, 16, 4), 1024, 0, stream>>>(qkv, qp, kp, vp, outp);
  gemm2_kernel<<<dim3(8, 128), 512, 0, stream>>>(ob, woT, outp);
}